// Round 6
// baseline (125.039 us; speedup 1.0000x reference)
//
#include <hip/hip_runtime.h>

#define B_SZ 8192
#define C_SZ 1024
#define NCLS 100
#define INV_T 0.25f
#define MAX_ITEMS 65536
#define NCH 8             // K chunks of 128 cols (256 B/row)

typedef unsigned int uint32;

using bf16x8 = __attribute__((ext_vector_type(8))) short;
using f32x16 = __attribute__((ext_vector_type(16))) float;

// round-to-nearest-even fp32 -> bf16 (inputs are positive, finite)
__device__ __forceinline__ unsigned short f2bf(float f) {
    uint32 u = __float_as_uint(f);
    u = u + 0x7fffu + ((u >> 16) & 1u);
    return (unsigned short)(u >> 16);
}

__device__ __forceinline__ void gload16_lds(const void* g, void* l) {
    __builtin_amdgcn_global_load_lds(
        (const __attribute__((address_space(1))) uint32*)g,
        (__attribute__((address_space(3))) uint32*)l, 16, 0, 0);
}

// Block 0: prep (zero accum/done, bucket rows by label via LDS atomics, build the
// (class, ti, tj) 32x32-tile item table). Blocks 1..B_SZ: row softmax.
__global__ __launch_bounds__(256) void softmax_prep_kernel(
        const float* __restrict__ x, const int* __restrict__ target,
        uint32* __restrict__ probs_bf, float* __restrict__ t,
        int* __restrict__ counts, int* __restrict__ lists,
        int* __restrict__ items, int* __restrict__ nitems,
        float* __restrict__ accum, int* __restrict__ done_ctr) {
    int tid = threadIdx.x;

    if (blockIdx.x == 0) {
        __shared__ int cnt[NCLS];
        __shared__ int tbase[NCLS];
        if (tid < NCLS) cnt[tid] = 0;
        if (tid == 0) { accum[0] = 0.0f; done_ctr[0] = 0; }
        __syncthreads();
        #pragma unroll 4
        for (int i = 0; i < B_SZ / 256; i++) {
            int r = i * 256 + tid;
            int lbl = target[r];
            if (lbl < 0) lbl = 0;
            if (lbl >= NCLS) lbl = NCLS - 1;   // defensive: keep in-bounds
            int slot = atomicAdd(&cnt[lbl], 1);
            lists[lbl * B_SZ + slot] = r;
        }
        __syncthreads();
        if (tid < NCLS) counts[tid] = cnt[tid];
        if (tid == 0) {
            int tot = 0;
            for (int k = 0; k < NCLS; k++) {
                int ng = (cnt[k] + 31) >> 5;
                tbase[k] = tot;
                tot += ng * ng;
            }
            nitems[0] = tot;
        }
        __syncthreads();
        if (tid < NCLS) {
            int ng = (cnt[tid] + 31) >> 5;
            int base = tbase[tid];
            int z = 0;
            for (int a = 0; a < ng; a++)
                for (int b = 0; b < ng; b++)
                    items[base + z++] = tid | (a << 8) | (b << 20);
        }
        return;
    }

    int row = blockIdx.x - 1;
    const float4* xr = (const float4*)(x + (size_t)row * C_SZ);
    float4 v = xr[tid];
    v.x *= INV_T; v.y *= INV_T; v.z *= INV_T; v.w *= INV_T;

    __shared__ float red[12];
    int wid = tid >> 6;

    float m = fmaxf(fmaxf(v.x, v.y), fmaxf(v.z, v.w));
    #pragma unroll
    for (int o = 32; o >= 1; o >>= 1) m = fmaxf(m, __shfl_xor(m, o, 64));
    if ((tid & 63) == 0) red[wid] = m;
    __syncthreads();
    m = fmaxf(fmaxf(red[0], red[1]), fmaxf(red[2], red[3]));

    float4 e;
    e.x = __expf(v.x - m); e.y = __expf(v.y - m);
    e.z = __expf(v.z - m); e.w = __expf(v.w - m);
    float s = (e.x + e.y) + (e.z + e.w);
    #pragma unroll
    for (int o = 32; o >= 1; o >>= 1) s += __shfl_xor(s, o, 64);
    if ((tid & 63) == 0) red[4 + wid] = s;
    __syncthreads();
    float Z = (red[4] + red[5]) + (red[6] + red[7]);
    float rZ = 1.0f / Z;

    float4 p;
    p.x = e.x * rZ + 1e-8f; p.y = e.y * rZ + 1e-8f;
    p.z = e.z * rZ + 1e-8f; p.w = e.w * rZ + 1e-8f;

    uint2 packed;
    packed.x = ((uint32)f2bf(p.y) << 16) | (uint32)f2bf(p.x);
    packed.y = ((uint32)f2bf(p.w) << 16) | (uint32)f2bf(p.z);
    ((uint2*)(probs_bf + (size_t)row * (C_SZ / 2)))[tid] = packed;

    float pl = p.x * __logf(p.x) + p.y * __logf(p.y) +
               p.z * __logf(p.z) + p.w * __logf(p.w);
    #pragma unroll
    for (int o = 32; o >= 1; o >>= 1) pl += __shfl_xor(pl, o, 64);
    if ((tid & 63) == 0) red[8 + wid] = pl;
    __syncthreads();
    if (tid == 0)
        t[row] = ((red[8] + red[9]) + (red[10] + red[11])) * (1.0f / C_SZ);
}

// One WAVE (64-thread block) per 32x32 tile: no barriers at all, so the K-chunk
// pipeline runs on counted vmcnt alone (T3/T4): chunk ch+1's 16 global_load_lds
// stay in flight (s_waitcnt vmcnt(16), never 0 until the tail) while chunk ch
// computes from the other LDS buffer. Round 5's barrier-per-chunk drained
// vmcnt(0) every 256 B of K (m97-style stall); this removes it. Staging source
// is XOR-swizzled per-lane global addrs (chunk-invariant, precomputed) with a
// linear LDS dest (rule 21); ds_read_b128 mirrors the swizzle (round-5 verified).
__global__ __launch_bounds__(64, 1) void pair_kernel(
        const char* __restrict__ probs, const float* __restrict__ t,
        const int* __restrict__ counts, const int* __restrict__ lists,
        const int* __restrict__ nitems, const int* __restrict__ items,
        float* __restrict__ accum, int* __restrict__ done_ctr,
        float* __restrict__ out) {
    __shared__ uint32 sT[2 * 4096];   // 2 bufs x (A 8KB + B 8KB) = 32 KB
    __shared__ int s_rid[64];

    int tid = threadIdx.x;
    int l = tid & 31;
    int h = tid >> 5;
    int NI = nitems[0];
    if (NI > MAX_ITEMS) NI = MAX_ITEMS;          // defensive
    float lacc = 0.0f;

    for (int it = blockIdx.x; it < NI; it += (int)gridDim.x) {
        int pk = items[it];
        int k = pk & 255;
        if (k >= NCLS) continue;                 // defensive
        int ti = (pk >> 8) & 0xfff;
        int tj = pk >> 20;
        int m = counts[k];
        if (m < 1) continue;                     // defensive
        if (m > B_SZ) m = B_SZ;

        // --- setup: 64 rids, one per lane (coalesced); t gathered for B side ---
        int myrow = (tid < 32) ? (ti * 32 + tid) : (tj * 32 + (tid - 32));
        if (myrow > m - 1) myrow = m - 1;
        int myrid = lists[k * B_SZ + myrow] & (B_SZ - 1);
        s_rid[tid] = myrid;
        int jrow = tj * 32 + l; if (jrow > m - 1) jrow = m - 1;
        float tjv = t[lists[k * B_SZ + jrow] & (B_SZ - 1)];
        __builtin_amdgcn_s_waitcnt(0);           // lgkm: s_rid visible (1 wave)

        // --- 16 chunk-invariant per-lane staging addresses ---
        // slot i (i<8: A rows 4i..4i+3; i>=8: B), lane ln: localrow = (i&7)*4+(ln>>4),
        // c16 = ln&15; src chunk = c16 ^ (localrow&7); LDS dest linear (row*256+c16*16).
        const char* gaddr[16];
        #pragma unroll
        for (int i = 0; i < 16; i++) {
            int localrow = (i & 7) * 4 + (tid >> 4);
            int rid = s_rid[(i >> 3) * 32 + localrow];
            int swz = (tid & 15) ^ (localrow & 7);
            gaddr[i] = probs + ((size_t)rid << 11) + (swz << 4);
        }
        // drain setup loads so vmcnt counting below is exact
        asm volatile("s_waitcnt vmcnt(0) lgkmcnt(0)" ::: "memory");
        __builtin_amdgcn_sched_barrier(0);

        #define STAGE(ch)                                                        \
            _Pragma("unroll")                                                    \
            for (int i = 0; i < 16; i++)                                         \
                gload16_lds(gaddr[i] + ((ch) << 8),                              \
                            (char*)sT + (((ch) & 1) << 14) + (i << 10));

        STAGE(0);
        STAGE(1);          // 32 loads in flight

        f32x16 acc = {};
        #pragma unroll
        for (int ch = 0; ch < NCH; ch++) {
            if (ch < NCH - 1) asm volatile("s_waitcnt vmcnt(16)" ::: "memory");
            else              asm volatile("s_waitcnt vmcnt(0)" ::: "memory");
            __builtin_amdgcn_sched_barrier(0);
            const uint32* base = sT + ((ch & 1) << 12);
            bf16x8 av[4], bv[4];
            #pragma unroll
            for (int ks = 0; ks < 4; ks++) {
                int ca = (2 * ks + h) ^ (l & 7);
                av[ks] = *(const bf16x8*)(base + l * 64 + ca * 4);
                bv[ks] = *(const bf16x8*)(base + 2048 + l * 64 + ca * 4);
            }
            #pragma unroll
            for (int ks = 0; ks < 4; ks++)
                acc = __builtin_amdgcn_mfma_f32_32x32x16_bf16(av[ks], bv[ks], acc, 0, 0, 0);
            if (ch + 2 < NCH) STAGE(ch + 2);   // overwrites buf just consumed (WAR
                                               // safe: ds_reads issued above)
        }
        #undef STAGE

        // epilogue: D col = lane&31 (B/tj side), row = (g&3)+8*(g>>2)+4*h (A/ti)
        int jl = tj * 32 + l;
        bool jv = jl < m;
        float local = 0.0f;
        #pragma unroll
        for (int g = 0; g < 16; g++) {
            int rowloc = (g & 3) + 8 * (g >> 2) + 4 * h;
            int il = ti * 32 + rowloc;
            if (jv && il < m && il != jl) {
                float kl = tjv - acc[g] * (1.0f / C_SZ);
                local += kl * kl;
            }
        }
        lacc += local;
    }

    #pragma unroll
    for (int o = 32; o >= 1; o >>= 1) lacc += __shfl_xor(lacc, o, 64);
    if (tid == 0) {
        atomicAdd(accum, lacc);
        __threadfence();
        if (atomicAdd(done_ctr, 1) == (int)gridDim.x - 1) {
            __threadfence();
            out[0] = atomicAdd(accum, 0.0f) * (1.0f / B_SZ);
        }
    }
}

extern "C" void kernel_launch(void* const* d_in, const int* in_sizes, int n_in,
                              void* d_out, int out_size, void* d_ws, size_t ws_size,
                              hipStream_t stream) {
    const float* x = (const float*)d_in[0];
    const int* target = (const int*)d_in[1];
    float* out = (float*)d_out;

    char* ws = (char*)d_ws;
    uint32* probs_bf = (uint32*)ws;                                   // 16 MB (B*C bf16)
    char* p = ws + (size_t)B_SZ * C_SZ * 2;
    float* t = (float*)p;            p += B_SZ * 4;                   // 32 KB
    int* counts = (int*)p;           p += 128 * 4;                    // 512 B
    int* nitems = (int*)p;           p += 16;                         // 4 B (+pad)
    int* lists = (int*)p;            p += (size_t)NCLS * B_SZ * 4;    // 3.2 MB
    int* items = (int*)p;            p += MAX_ITEMS * 4;              // 256 KB
    float* accum = (float*)p;        p += 16;                         // 4 B (+pad)
    int* done_ctr = (int*)p;                                          // 4 B

    softmax_prep_kernel<<<B_SZ + 1, 256, 0, stream>>>(x, target, probs_bf, t,
                                                      counts, lists, items, nitems,
                                                      accum, done_ctr);
    pair_kernel<<<1024, 64, 0, stream>>>((const char*)probs_bf, t, counts, lists,
                                         nitems, items, accum, done_ctr, out);
}

// Round 7
// 97.016 us; speedup vs baseline: 1.2888x; 1.2888x over previous
//
#include <hip/hip_runtime.h>

#define B_SZ 8192
#define C_SZ 1024
#define NCLS 100
#define INV_T 0.25f
#define MAX_ITEMS 65536
#define NCH 8             // K chunks of 128 cols (256 B/row)
#define GRP 128           // rows per group: whole class (m~82) in one strip
#define PAIR_GRID 128

typedef unsigned int uint32;

using bf16x8 = __attribute__((ext_vector_type(8))) short;
using f32x16 = __attribute__((ext_vector_type(16))) float;

// round-to-nearest-even fp32 -> bf16 (inputs are positive, finite)
__device__ __forceinline__ unsigned short f2bf(float f) {
    uint32 u = __float_as_uint(f);
    u = u + 0x7fffu + ((u >> 16) & 1u);
    return (unsigned short)(u >> 16);
}

__device__ __forceinline__ void gload16_lds(const void* g, void* l) {
    __builtin_amdgcn_global_load_lds(
        (const __attribute__((address_space(1))) uint32*)g,
        (__attribute__((address_space(3))) uint32*)l, 16, 0, 0);
}

// Block 0: prep (zero accum/done, bucket rows by label, build (k,gi<=gj) 128-row
// group-pair item table). Blocks 1..B_SZ: row softmax(x/T)+1e-8 -> bf16, t[row].
__global__ __launch_bounds__(256) void softmax_prep_kernel(
        const float* __restrict__ x, const int* __restrict__ target,
        uint32* __restrict__ probs_bf, float* __restrict__ t,
        int* __restrict__ counts, int* __restrict__ lists,
        int* __restrict__ items, int* __restrict__ nitems,
        float* __restrict__ accum, int* __restrict__ done_ctr) {
    int tid = threadIdx.x;

    if (blockIdx.x == 0) {
        __shared__ int cnt[NCLS];
        __shared__ int tbase[NCLS];
        if (tid < NCLS) cnt[tid] = 0;
        if (tid == 0) { accum[0] = 0.0f; done_ctr[0] = 0; }
        __syncthreads();
        #pragma unroll 4
        for (int i = 0; i < B_SZ / 256; i++) {
            int r = i * 256 + tid;
            int lbl = target[r];
            if (lbl < 0) lbl = 0;
            if (lbl >= NCLS) lbl = NCLS - 1;   // defensive
            int slot = atomicAdd(&cnt[lbl], 1);
            lists[lbl * B_SZ + slot] = r;
        }
        __syncthreads();
        if (tid < NCLS) counts[tid] = cnt[tid];
        if (tid == 0) {
            int tot = 0;
            for (int k = 0; k < NCLS; k++) {
                int ng = (cnt[k] + GRP - 1) / GRP;
                tbase[k] = tot;
                tot += ng * (ng + 1) / 2;      // upper-triangle group pairs only
            }
            nitems[0] = tot;
        }
        __syncthreads();
        if (tid < NCLS) {
            int ng = (cnt[tid] + GRP - 1) / GRP;
            int base = tbase[tid];
            int z = 0;
            for (int a = 0; a < ng; a++)
                for (int b = a; b < ng; b++)
                    items[base + z++] = tid | (a << 8) | (b << 20);
        }
        return;
    }

    int row = blockIdx.x - 1;
    const float4* xr = (const float4*)(x + (size_t)row * C_SZ);
    float4 v = xr[tid];
    v.x *= INV_T; v.y *= INV_T; v.z *= INV_T; v.w *= INV_T;

    __shared__ float red[12];
    int wid = tid >> 6;

    float m = fmaxf(fmaxf(v.x, v.y), fmaxf(v.z, v.w));
    #pragma unroll
    for (int o = 32; o >= 1; o >>= 1) m = fmaxf(m, __shfl_xor(m, o, 64));
    if ((tid & 63) == 0) red[wid] = m;
    __syncthreads();
    m = fmaxf(fmaxf(red[0], red[1]), fmaxf(red[2], red[3]));

    float4 e;
    e.x = __expf(v.x - m); e.y = __expf(v.y - m);
    e.z = __expf(v.z - m); e.w = __expf(v.w - m);
    float s = (e.x + e.y) + (e.z + e.w);
    #pragma unroll
    for (int o = 32; o >= 1; o >>= 1) s += __shfl_xor(s, o, 64);
    if ((tid & 63) == 0) red[4 + wid] = s;
    __syncthreads();
    float Z = (red[4] + red[5]) + (red[6] + red[7]);
    float rZ = 1.0f / Z;

    float4 p;
    p.x = e.x * rZ + 1e-8f; p.y = e.y * rZ + 1e-8f;
    p.z = e.z * rZ + 1e-8f; p.w = e.w * rZ + 1e-8f;

    uint2 packed;
    packed.x = ((uint32)f2bf(p.y) << 16) | (uint32)f2bf(p.x);
    packed.y = ((uint32)f2bf(p.w) << 16) | (uint32)f2bf(p.z);
    ((uint2*)(probs_bf + (size_t)row * (C_SZ / 2)))[tid] = packed;

    float pl = p.x * __logf(p.x) + p.y * __logf(p.y) +
               p.z * __logf(p.z) + p.w * __logf(p.w);
    #pragma unroll
    for (int o = 32; o >= 1; o >>= 1) pl += __shfl_xor(pl, o, 64);
    if ((tid & 63) == 0) red[8 + wid] = pl;
    __syncthreads();
    if (tid == 0)
        t[row] = ((red[8] + red[9]) + (red[10] + red[11])) * (1.0f / C_SZ);
}

// One 512-thread block (8 waves) per (class, gi<=gj) 128-row group pair.
// Rounds 2-6 showed pair perf tracks FETCH_SIZE at a fixed ~0.9 TB/s scatter
// service rate -> minimize traffic: stage each group's rows ONCE per K-chunk
// (coalesced, 32KB/strip, double-buffered) and compute the UPPER-TRIANGLE
// tile-pairs only (cross is symmetric: one tile gives kl[i,j]^2 + kl[j,i]^2).
// Sync: raw s_barrier + per-wave counted vmcnt (m201 template) -- raw barrier
// does NOT drain vmcnt, so next chunk's global_load_lds stay in flight.
__global__ __launch_bounds__(512, 2) void pair_kernel(
        const char* __restrict__ probs, const float* __restrict__ t,
        const int* __restrict__ counts, const int* __restrict__ lists,
        const int* __restrict__ nitems, const int* __restrict__ items,
        float* __restrict__ accum, int* __restrict__ done_ctr,
        float* __restrict__ out) {
    __shared__ char sAB[2][2][32768];   // [dbuf][strip A/B][128 rows x 256 B] = 128 KB
    __shared__ int s_ridA[GRP];
    __shared__ int s_ridB[GRP];
    __shared__ float s_tA[GRP];
    __shared__ float s_tB[GRP];
    __shared__ float s_wsum[8];

    int tid = threadIdx.x;
    int wv = tid >> 6;
    int ln = tid & 63;
    int l = ln & 31;
    int h = ln >> 5;
    int NI = nitems[0];
    if (NI > MAX_ITEMS) NI = MAX_ITEMS;          // defensive
    float lacc = 0.0f;

    for (int it = blockIdx.x; it < NI; it += (int)gridDim.x) {
        int pk = items[it];
        int k = pk & 255;
        if (k >= NCLS) continue;                 // defensive
        int gi = (pk >> 8) & 0xfff;
        int gj = pk >> 20;
        int m = counts[k];
        if (m < 1) continue;                     // defensive
        if (m > B_SZ) m = B_SZ;
        bool same_strip = (gi == gj);

        __syncthreads();   // prev item done with LDS; drains vmcnt to 0 (exact counting)
        if (tid < GRP) {
            int which = gi * GRP + tid; if (which > m - 1) which = m - 1;
            int r = lists[k * B_SZ + which] & (B_SZ - 1);
            s_ridA[tid] = r;
            s_tA[tid] = t[r];
        } else if (tid < 2 * GRP) {
            int rb = tid - GRP;
            int which = gj * GRP + rb; if (which > m - 1) which = m - 1;
            int r = lists[k * B_SZ + which] & (B_SZ - 1);
            s_ridB[rb] = r;
            s_tB[rb] = t[r];
        }
        __syncthreads();   // rids visible; vmcnt drained again

        int rowsA = m - gi * GRP; if (rowsA > GRP) rowsA = GRP;
        int rowsB = m - gj * GRP; if (rowsB > GRP) rowsB = GRP;
        int ntA = (rowsA + 31) >> 5;
        int ntB = (rowsB + 31) >> 5;

        // per-wave tile-pair assignment (wave-uniform)
        int P = same_strip ? (ntA * (ntA + 1)) / 2 : ntA * ntB;
        int tta[2], ttb[2], pv[2];
        #pragma unroll
        for (int slot = 0; slot < 2; slot++) {
            int p = wv + slot * 8;
            pv[slot] = (p < P);
            int pp = pv[slot] ? p : 0;
            int a = 0, b = 0;
            if (same_strip) {
                int rem = pp, len = ntA;
                while (rem >= len) { rem -= len; a++; len--; }
                b = a + rem;
            } else {
                a = pp / ntB; b = pp % ntB;
            }
            tta[slot] = a; ttb[slot] = b;
        }

        // chunk-invariant per-lane staging addresses (XOR-swizzled source,
        // linear LDS dest -- rule 21; read side mirrors the XOR)
        const char* gA[4];
        const char* gB[4];
        #pragma unroll
        for (int s = 0; s < 4; s++) {
            int row = s * 32 + wv * 4 + (ln >> 4);
            int c16 = ln & 15;
            int off = ((c16 ^ (row & 7)) << 4);
            gA[s] = probs + ((size_t)s_ridA[row] << 11) + off;
            gB[s] = probs + ((size_t)s_ridB[row] << 11) + off;
        }

        #define STAGE_A(ch, db)                                                \
            _Pragma("unroll")                                                  \
            for (int s = 0; s < 4; s++)                                        \
                gload16_lds(gA[s] + ((ch) << 8), &sAB[db][0][s * 8192 + wv * 1024]);
        #define STAGE_B(ch, db)                                                \
            _Pragma("unroll")                                                  \
            for (int s = 0; s < 4; s++)                                        \
                gload16_lds(gB[s] + ((ch) << 8), &sAB[db][1][s * 8192 + wv * 1024]);

        #define COMPUTE(db, bs)                                                \
            { const char* bufA_ = &sAB[db][0][0];                              \
              const char* bufB_ = &sAB[db][bs][0];                             \
              _Pragma("unroll")                                                \
              for (int slot = 0; slot < 2; slot++) {                           \
                  if (pv[slot]) {                                              \
                      _Pragma("unroll")                                        \
                      for (int ks = 0; ks < 4; ks++) {                         \
                          int ca = ((2 * ks + h) ^ (l & 7)) << 4;              \
                          bf16x8 av = *(const bf16x8*)(bufA_ + (tta[slot] * 32 + l) * 256 + ca); \
                          bf16x8 bv = *(const bf16x8*)(bufB_ + (ttb[slot] * 32 + l) * 256 + ca); \
                          acc[slot] = __builtin_amdgcn_mfma_f32_32x32x16_bf16(av, bv, acc[slot], 0, 0, 0); \
                      }                                                        \
                  }                                                            \
              } }

        f32x16 acc[2] = {};
        if (same_strip) {
            STAGE_A(0, 0);                     // 4 loads/wave in flight
            #pragma unroll 1
            for (int ch = 0; ch < NCH; ch++) {
                int db = ch & 1;
                if (ch + 1 < NCH) {
                    STAGE_A(ch + 1, db ^ 1);   // 8 in flight
                    asm volatile("s_waitcnt vmcnt(4)" ::: "memory");
                } else {
                    asm volatile("s_waitcnt vmcnt(0)" ::: "memory");
                }
                __builtin_amdgcn_sched_barrier(0);
                __builtin_amdgcn_s_barrier();          // chunk ch fully in LDS
                __builtin_amdgcn_sched_barrier(0);
                COMPUTE(db, 0);
                __builtin_amdgcn_sched_barrier(0);
                __builtin_amdgcn_s_barrier();          // reads done before overwrite
            }
        } else {
            STAGE_A(0, 0); STAGE_B(0, 0);      // 8 in flight
            #pragma unroll 1
            for (int ch = 0; ch < NCH; ch++) {
                int db = ch & 1;
                if (ch + 1 < NCH) {
                    STAGE_A(ch + 1, db ^ 1); STAGE_B(ch + 1, db ^ 1);  // 16 in flight
                    asm volatile("s_waitcnt vmcnt(8)" ::: "memory");
                } else {
                    asm volatile("s_waitcnt vmcnt(0)" ::: "memory");
                }
                __builtin_amdgcn_sched_barrier(0);
                __builtin_amdgcn_s_barrier();
                __builtin_amdgcn_sched_barrier(0);
                COMPUTE(db, 1);
                __builtin_amdgcn_sched_barrier(0);
                __builtin_amdgcn_s_barrier();
            }
        }
        #undef STAGE_A
        #undef STAGE_B
        #undef COMPUTE

        // epilogue. D layout: col = lane&31 (B side), row = (g&3)+8*(g>>2)+4*h (A).
        // diag tile: single orientation (both orderings present in tile).
        // strictly-upper tile: add both (t_col - c)^2 and (t_row - c)^2.
        float local = 0.0f;
        #pragma unroll
        for (int slot = 0; slot < 2; slot++) {
            if (pv[slot]) {
                bool dtile = same_strip && (tta[slot] == ttb[slot]);
                int jloc = ttb[slot] * 32 + l;
                int jl = gj * GRP + jloc;
                bool jv = jl < m;
                float tcol = s_tB[jloc];
                #pragma unroll
                for (int g = 0; g < 16; g++) {
                    int rowloc = (g & 3) + 8 * (g >> 2) + 4 * h;
                    int iloc = tta[slot] * 32 + rowloc;
                    int il = gi * GRP + iloc;
                    bool iv = il < m;
                    float c = acc[slot][g] * (1.0f / C_SZ);
                    if (dtile) {
                        if (iv && jv && il != jl) {
                            float kl = tcol - c; local += kl * kl;
                        }
                    } else {
                        if (iv && jv) {
                            float k1 = tcol - c;
                            float k2 = s_tA[iloc] - c;
                            local += k1 * k1 + k2 * k2;
                        }
                    }
                }
            }
        }
        lacc += local;
    }

    #pragma unroll
    for (int o = 32; o >= 1; o >>= 1) lacc += __shfl_xor(lacc, o, 64);
    __syncthreads();
    if (ln == 0) s_wsum[wv] = lacc;
    __syncthreads();
    if (tid == 0) {
        float tot = 0.0f;
        #pragma unroll
        for (int w = 0; w < 8; w++) tot += s_wsum[w];
        atomicAdd(accum, tot);
        __threadfence();
        if (atomicAdd(done_ctr, 1) == (int)gridDim.x - 1) {
            __threadfence();
            out[0] = atomicAdd(accum, 0.0f) * (1.0f / B_SZ);
        }
    }
}

extern "C" void kernel_launch(void* const* d_in, const int* in_sizes, int n_in,
                              void* d_out, int out_size, void* d_ws, size_t ws_size,
                              hipStream_t stream) {
    const float* x = (const float*)d_in[0];
    const int* target = (const int*)d_in[1];
    float* out = (float*)d_out;

    char* ws = (char*)d_ws;
    uint32* probs_bf = (uint32*)ws;                                   // 16 MB (B*C bf16)
    char* p = ws + (size_t)B_SZ * C_SZ * 2;
    float* t = (float*)p;            p += B_SZ * 4;                   // 32 KB
    int* counts = (int*)p;           p += 128 * 4;                    // 512 B
    int* nitems = (int*)p;           p += 16;                         // 4 B (+pad)
    int* lists = (int*)p;            p += (size_t)NCLS * B_SZ * 4;    // 3.2 MB
    int* items = (int*)p;            p += MAX_ITEMS * 4;              // 256 KB
    float* accum = (float*)p;        p += 16;                         // 4 B (+pad)
    int* done_ctr = (int*)p;                                          // 4 B

    softmax_prep_kernel<<<B_SZ + 1, 256, 0, stream>>>(x, target, probs_bf, t,
                                                      counts, lists, items, nitems,
                                                      accum, done_ctr);
    pair_kernel<<<PAIR_GRID, 512, 0, stream>>>((const char*)probs_bf, t, counts,
                                               lists, nitems, items, accum,
                                               done_ctr, out);
}